// Round 4
// baseline (11353.223 us; speedup 1.0000x reference)
//
#include <hip/hip_runtime.h>
#include <math.h>

// Problem geometry — all f32 (reference is pure jnp.float32, outputs f32)
#define NBLK 64          // 4x4x4 coarse blocks
#define SUBTREE_FLOATS (512ull*32ull*1728ull)   // 28,311,552

__device__ __forceinline__ float relu_bn(float acc, float g, float b) {
    float s = g * rsqrtf(1.0f + 1e-5f);
    float v = acc * s + b;
    return v > 0.f ? v : 0.f;
}

// ---------------- prediction path ----------------
// conv(32->16,k3) + BN + ReLU + maxpool2 : [64,32,12^3] -> h0 [64,16,5^3]
__global__ void pred_p0(const float* __restrict__ prev, const float* __restrict__ w,
                        const float* __restrict__ g, const float* __restrict__ b,
                        float* __restrict__ h0) {
    int blk = blockIdx.x;              // n*16 + co
    int n = blk >> 4, co = blk & 15;
    __shared__ float ws[32 * 27];
    for (int i = threadIdx.x; i < 32 * 27; i += blockDim.x) ws[i] = w[co * 864 + i];
    __syncthreads();
    int t = threadIdx.x;
    if (t >= 125) return;
    int pz = t / 25, py = (t / 5) % 5, px = t % 5;
    float sc = g[co] * rsqrtf(1.0f + 1e-5f);
    float bi = b[co];
    float m = -INFINITY;
    const float* pb = prev + (size_t)n * 32 * 1728;
    for (int dz = 0; dz < 2; dz++)
    for (int dy = 0; dy < 2; dy++)
    for (int dx = 0; dx < 2; dx++) {
        int z = 2 * pz + dz, y = 2 * py + dy, x = 2 * px + dx;
        float acc = 0.f;
        for (int ci = 0; ci < 32; ci++) {
            const float* pc = pb + ci * 1728 + z * 144 + y * 12 + x;
            const float* wc = ws + ci * 27;
            #pragma unroll
            for (int kz = 0; kz < 3; kz++)
            #pragma unroll
            for (int ky = 0; ky < 3; ky++)
            #pragma unroll
            for (int kx = 0; kx < 3; kx++)
                acc += pc[kz * 144 + ky * 12 + kx] * wc[kz * 9 + ky * 3 + kx];
        }
        float v = acc * sc + bi; v = v > 0.f ? v : 0.f;
        m = fmaxf(m, v);
    }
    h0[blk * 125 + t] = m;
}

// conv(16->8,k3)+BN+ReLU on 5^3 -> 3^3, pool2 -> 1, linear(8->3)
__global__ void pred_p1(const float* __restrict__ h0, const float* __restrict__ w,
                        const float* __restrict__ g, const float* __restrict__ b,
                        const float* __restrict__ wlin, const float* __restrict__ blin,
                        float* __restrict__ pred_out) {
    int n = blockIdx.x;
    __shared__ float conv[216];
    __shared__ float pooled[8];
    int t = threadIdx.x;
    if (t < 216) {
        int co = t / 27, r = t % 27;
        int oz = r / 9, oy = (r / 3) % 3, ox = r % 3;
        float acc = 0.f;
        for (int ci = 0; ci < 16; ci++) {
            const float* hc = h0 + (n * 16 + ci) * 125 + oz * 25 + oy * 5 + ox;
            const float* wc = w + (co * 16 + ci) * 27;
            #pragma unroll
            for (int kz = 0; kz < 3; kz++)
            #pragma unroll
            for (int ky = 0; ky < 3; ky++)
            #pragma unroll
            for (int kx = 0; kx < 3; kx++)
                acc += hc[kz * 25 + ky * 5 + kx] * wc[kz * 9 + ky * 3 + kx];
        }
        conv[t] = relu_bn(acc, g[co], b[co]);
    }
    __syncthreads();
    if (t < 8) {
        float m = -INFINITY;
        for (int dz = 0; dz < 2; dz++)
        for (int dy = 0; dy < 2; dy++)
        for (int dx = 0; dx < 2; dx++)
            m = fmaxf(m, conv[t * 27 + dz * 9 + dy * 3 + dx]);
        pooled[t] = m;
    }
    __syncthreads();
    if (t < 3) {
        float acc = blin[t];
        #pragma unroll
        for (int j = 0; j < 8; j++) acc += pooled[j] * wlin[t * 8 + j];
        pred_out[n * 3 + t] = acc;
    }
}

// ---------------- main path ----------------
// JAX lax.conv_transpose(..., 'IODHW', transpose_kernel=True) derived semantics:
//   up[n, co, 2i+k] += prev[n, ci, i] * w_up[co, ci, k]
// NOTE: contraction is over w_up dim 1; output channel indexes dim 0.
// (Torch-style w[ci,co,k] was the Round-1 bug.)
__global__ void upsample_k(const float* __restrict__ prev, const float* __restrict__ wup,
                           float* __restrict__ U, int n0, int total) {
    int idx = blockIdx.x * blockDim.x + threadIdx.x;
    if (idx >= total) return;
    int r  = idx % 17576;                 // 26^3
    int co = (idx / 17576) & 31;
    int nl = idx / (17576 * 32);
    int oz = r / 676, oy = (r / 26) % 26, ox = r % 26;
    int n = n0 + nl;

    int kz[2], iz[2], nz = 0;
    { int p = oz & 1, i0 = oz >> 1;
      if (i0 < 12)     { kz[nz] = p;     iz[nz] = i0;     nz++; }
      if (i0 - 1 >= 0) { kz[nz] = p + 2; iz[nz] = i0 - 1; nz++; } }
    int ky[2], iy[2], ny = 0;
    { int p = oy & 1, i0 = oy >> 1;
      if (i0 < 12)     { ky[ny] = p;     iy[ny] = i0;     ny++; }
      if (i0 - 1 >= 0) { ky[ny] = p + 2; iy[ny] = i0 - 1; ny++; } }
    int kx[2], ix[2], nx = 0;
    { int p = ox & 1, i0 = ox >> 1;
      if (i0 < 12)     { kx[nx] = p;     ix[nx] = i0;     nx++; }
      if (i0 - 1 >= 0) { kx[nx] = p + 2; ix[nx] = i0 - 1; nx++; } }

    float acc = 0.f;
    const float* pb = prev + (size_t)n * 32 * 1728;
    const float* wb = wup + (size_t)co * 2048;     // w_up[co, :, :,:,:]
    for (int a = 0; a < nz; a++)
    for (int bb = 0; bb < ny; bb++)
    for (int cc = 0; cc < nx; cc++) {
        int ioff = iz[a] * 144 + iy[bb] * 12 + ix[cc];
        int koff = kz[a] * 16 + ky[bb] * 4 + kx[cc];
        #pragma unroll 8
        for (int ci = 0; ci < 32; ci++)
            acc += pb[ci * 1728 + ioff] * wb[ci * 64 + koff];
    }
    U[idx] = acc;
}

// conv0: Cin=33 (ch 32 = tsdf slice), 26^3 -> 24^3, BN+ReLU
__global__ void conv0_k(const float* __restrict__ U, const float* __restrict__ tsdf,
                        const float* __restrict__ w, const float* __restrict__ g,
                        const float* __restrict__ b, float* __restrict__ X0, int n0) {
    int blk = blockIdx.x;
    int oz = blk % 24;
    int co = (blk / 24) & 31;
    int nl = blk / (24 * 32);
    __shared__ float ws[33 * 27];
    for (int i = threadIdx.x; i < 33 * 27; i += blockDim.x) ws[i] = w[co * 891 + i];
    __syncthreads();
    int t = threadIdx.x;          // 576 = 24*24 exactly
    int oy = t / 24, ox = t % 24;
    float acc = 0.f;
    const float* ub = U + (size_t)nl * 32 * 17576;
    for (int ci = 0; ci < 32; ci++) {
        const float* uc = ub + ci * 17576 + oz * 676 + oy * 26 + ox;
        const float* wc = ws + ci * 27;
        #pragma unroll
        for (int kz = 0; kz < 3; kz++)
        #pragma unroll
        for (int ky = 0; ky < 3; ky++)
        #pragma unroll
        for (int kx = 0; kx < 3; kx++)
            acc += uc[kz * 676 + ky * 26 + kx] * wc[kz * 9 + ky * 3 + kx];
    }
    {   // tsdf channel: slice origin (a,b,c)*16 of 74^3 volume
        int n = n0 + nl;
        int A = (n >> 4) * 16, B = ((n >> 2) & 3) * 16, C = (n & 3) * 16;
        const float* tz = tsdf + (size_t)(A + oz) * 5476 + (B + oy) * 74 + (C + ox);
        const float* wc = ws + 32 * 27;
        #pragma unroll
        for (int kz = 0; kz < 3; kz++)
        #pragma unroll
        for (int ky = 0; ky < 3; ky++)
        #pragma unroll
        for (int kx = 0; kx < 3; kx++)
            acc += tz[kz * 5476 + ky * 74 + kx] * wc[kz * 9 + ky * 3 + kx];
    }
    X0[(((size_t)nl * 32 + co) * 24 + oz) * 576 + t] = relu_bn(acc, g[co], b[co]);
}

// conv1: 24^3 -> 22^3, BN+ReLU
__global__ void conv1_k(const float* __restrict__ X0, const float* __restrict__ w,
                        const float* __restrict__ g, const float* __restrict__ b,
                        float* __restrict__ X1) {
    int blk = blockIdx.x;
    int oz = blk % 22;
    int co = (blk / 22) & 31;
    int nl = blk / (22 * 32);
    __shared__ float ws[32 * 27];
    for (int i = threadIdx.x; i < 864; i += blockDim.x) ws[i] = w[co * 864 + i];
    __syncthreads();
    int t = threadIdx.x;
    if (t >= 484) return;
    int oy = t / 22, ox = t % 22;
    float acc = 0.f;
    const float* xb = X0 + (size_t)nl * 32 * 13824;
    for (int ci = 0; ci < 32; ci++) {
        const float* xc = xb + ci * 13824 + oz * 576 + oy * 24 + ox;
        const float* wc = ws + ci * 27;
        #pragma unroll
        for (int kz = 0; kz < 3; kz++)
        #pragma unroll
        for (int ky = 0; ky < 3; ky++)
        #pragma unroll
        for (int kx = 0; kx < 3; kx++)
            acc += xc[kz * 576 + ky * 24 + kx] * wc[kz * 9 + ky * 3 + kx];
    }
    X1[(((size_t)nl * 32 + co) * 22 + oz) * 484 + t] = relu_bn(acc, g[co], b[co]);
}

// conv2: 22^3 -> 20^3, BN+ReLU, fused split_tree scatter into d_out (f32)
__global__ void conv2s_k(const float* __restrict__ X1, const float* __restrict__ w,
                         const float* __restrict__ g, const float* __restrict__ b,
                         float* __restrict__ out, int n0) {
    int blk = blockIdx.x;
    int oz = blk % 20;
    int co = (blk / 20) & 31;
    int nl = blk / (20 * 32);
    __shared__ float ws[32 * 27];
    for (int i = threadIdx.x; i < 864; i += blockDim.x) ws[i] = w[co * 864 + i];
    __syncthreads();
    int t = threadIdx.x;
    if (t >= 400) return;
    int oy = t / 20, ox = t % 20;
    float acc = 0.f;
    const float* xb = X1 + (size_t)nl * 32 * 10648;
    for (int ci = 0; ci < 32; ci++) {
        const float* xc = xb + ci * 10648 + oz * 484 + oy * 22 + ox;
        const float* wc = ws + ci * 27;
        #pragma unroll
        for (int kz = 0; kz < 3; kz++)
        #pragma unroll
        for (int ky = 0; ky < 3; ky++)
        #pragma unroll
        for (int kx = 0; kx < 3; kx++)
            acc += xc[kz * 484 + ky * 22 + kx] * wc[kz * 9 + ky * 3 + kx];
    }
    float v = relu_bn(acc, g[co], b[co]);
    int n = n0 + nl;
    // children: offsets {0,8}^3, child spatial 12, s = za*4 + yb*2 + xc
    #pragma unroll
    for (int za = 0; za < 2; za++) {
        int z = oz - za * 8; if (z < 0 || z >= 12) continue;
        #pragma unroll
        for (int yb = 0; yb < 2; yb++) {
            int y = oy - yb * 8; if (y < 0 || y >= 12) continue;
            #pragma unroll
            for (int xc = 0; xc < 2; xc++) {
                int x = ox - xc * 8; if (x < 0 || x >= 12) continue;
                int s = za * 4 + yb * 2 + xc;
                out[((((size_t)n * 8 + s) * 32 + co) * 12 + z) * 144 + y * 12 + x] = v;
            }
        }
    }
}

extern "C" void kernel_launch(void* const* d_in, const int* in_sizes, int n_in,
                              void* d_out, int out_size, void* d_ws, size_t ws_size,
                              hipStream_t stream) {
    const float* prev  = (const float*)d_in[0];
    const float* tsdf  = (const float*)d_in[1];
    const float* w_up  = (const float*)d_in[2];
    const float* w_c0  = (const float*)d_in[3];
    const float* g_c0  = (const float*)d_in[4];
    const float* b_c0  = (const float*)d_in[5];
    const float* w_c1  = (const float*)d_in[6];
    const float* g_c1  = (const float*)d_in[7];
    const float* b_c1  = (const float*)d_in[8];
    const float* w_c2  = (const float*)d_in[9];
    const float* g_c2  = (const float*)d_in[10];
    const float* b_c2  = (const float*)d_in[11];
    const float* w_p0  = (const float*)d_in[12];
    const float* g_p0  = (const float*)d_in[13];
    const float* b_p0  = (const float*)d_in[14];
    const float* w_p1  = (const float*)d_in[15];
    const float* g_p1  = (const float*)d_in[16];
    const float* b_p1  = (const float*)d_in[17];
    const float* w_lin = (const float*)d_in[18];
    const float* b_lin = (const float*)d_in[19];

    float* out = (float*)d_out;
    float* ws  = (float*)d_ws;

    // ---- prediction path (all 64 blocks at once) ----
    float* h0 = ws;                       // 64*16*125 = 128000 floats
    pred_p0<<<64 * 16, 128, 0, stream>>>(prev, w_p0, g_p0, b_p0, h0);
    pred_p1<<<64, 256, 0, stream>>>(h0, w_p1, g_p1, b_p1, w_lin, b_lin,
                                    out + SUBTREE_FLOATS);

    // ---- main path, chunked over coarse blocks to bound workspace ----
    int chunk = 16;
    while (chunk > 1) {
        size_t need = (128000ull + (size_t)chunk * 32ull * (17576ull + 13824ull + 10648ull))
                      * sizeof(float);
        if (need <= ws_size) break;
        chunk >>= 1;
    }
    float* bufU  = ws + 128000;
    float* bufX0 = bufU  + (size_t)chunk * 32 * 17576;
    float* bufX1 = bufX0 + (size_t)chunk * 32 * 13824;

    for (int n0 = 0; n0 < NBLK; n0 += chunk) {
        int totalU = chunk * 32 * 17576;
        upsample_k<<<(totalU + 255) / 256, 256, 0, stream>>>(prev, w_up, bufU, n0, totalU);
        conv0_k <<<chunk * 32 * 24, 576, 0, stream>>>(bufU, tsdf, w_c0, g_c0, b_c0, bufX0, n0);
        conv1_k <<<chunk * 32 * 22, 512, 0, stream>>>(bufX0, w_c1, g_c1, b_c1, bufX1);
        conv2s_k<<<chunk * 32 * 20, 448, 0, stream>>>(bufX1, w_c2, g_c2, b_c2, out, n0);
    }
}

// Round 5
// 4832.984 us; speedup vs baseline: 2.3491x; 2.3491x over previous
//
#include <hip/hip_runtime.h>
#include <math.h>

// All f32; output buffer f32. Verified-correct math from Round 4.
#define NBLK 64
#define SUBTREE_FLOATS (512ull*32ull*1728ull)   // 28,311,552

__device__ __forceinline__ float relu_bn(float acc, float g, float b) {
    float s = g * rsqrtf(1.0f + 1e-5f);
    float v = acc * s + b;
    return v > 0.f ? v : 0.f;
}

// ---------------- prediction path ----------------
// conv(32->16,k3)+BN+ReLU+pool2: [64,32,12^3] -> h0 [64,16,5^3]
// thread = (oy,ox) of the 10x10 conv plane, full 10-deep z-column in registers.
__global__ void pred_p0(const float* __restrict__ prev, const float* __restrict__ w,
                        const float* __restrict__ g, const float* __restrict__ b,
                        float* __restrict__ h0) {
    int blk = blockIdx.x;              // n*16 + co
    int n = blk >> 4, co = blk & 15;
    int t = threadIdx.x;
    __shared__ float pz5[10 * 10 * 5];
    if (t < 100) {
        int oy = t / 10, ox = t % 10;
        float acc[10];
        #pragma unroll
        for (int i = 0; i < 10; i++) acc[i] = 0.f;
        const float* pb = prev + (size_t)n * 32 * 1728;
        const float* wb = w + co * 864;
        for (int ci = 0; ci < 32; ci++) {
            float wr[27];
            #pragma unroll
            for (int j = 0; j < 27; j++) wr[j] = wb[ci * 27 + j];   // uniform -> s_load
            const float* pc = pb + ci * 1728;
            #pragma unroll
            for (int ky = 0; ky < 3; ky++) {
                #pragma unroll
                for (int kx = 0; kx < 3; kx++) {
                    const float* col = pc + (oy + ky) * 12 + (ox + kx);
                    #pragma unroll
                    for (int j = 0; j < 12; j++) {
                        float u = col[j * 144];
                        #pragma unroll
                        for (int kz = 0; kz < 3; kz++) {
                            int zz = j - kz;                  // compile-time guard
                            if (zz >= 0 && zz < 10)
                                acc[zz] += u * wr[kz * 9 + ky * 3 + kx];
                        }
                    }
                }
            }
        }
        float sc = g[co] * rsqrtf(1.0f + 1e-5f);
        float bi = b[co];
        #pragma unroll
        for (int p = 0; p < 5; p++) {
            float a0 = acc[2 * p]     * sc + bi; a0 = a0 > 0.f ? a0 : 0.f;
            float a1 = acc[2 * p + 1] * sc + bi; a1 = a1 > 0.f ? a1 : 0.f;
            pz5[(oy * 10 + ox) * 5 + p] = fmaxf(a0, a1);
        }
    }
    __syncthreads();
    if (t < 125) {
        int pz = t / 25, py = (t / 5) % 5, px = t % 5;
        float m = -INFINITY;
        #pragma unroll
        for (int dy = 0; dy < 2; dy++)
        #pragma unroll
        for (int dx = 0; dx < 2; dx++)
            m = fmaxf(m, pz5[((2 * py + dy) * 10 + 2 * px + dx) * 5 + pz]);
        h0[(n * 16 + co) * 125 + pz * 25 + py * 5 + px] = m;
    }
}

// conv(16->8,k3)+BN+ReLU on 5^3 -> 3^3, pool2 -> 1, linear(8->3)  (tiny, unchanged)
__global__ void pred_p1(const float* __restrict__ h0, const float* __restrict__ w,
                        const float* __restrict__ g, const float* __restrict__ b,
                        const float* __restrict__ wlin, const float* __restrict__ blin,
                        float* __restrict__ pred_out) {
    int n = blockIdx.x;
    __shared__ float conv[216];
    __shared__ float pooled[8];
    int t = threadIdx.x;
    if (t < 216) {
        int co = t / 27, r = t % 27;
        int oz = r / 9, oy = (r / 3) % 3, ox = r % 3;
        float acc = 0.f;
        for (int ci = 0; ci < 16; ci++) {
            const float* hc = h0 + (n * 16 + ci) * 125 + oz * 25 + oy * 5 + ox;
            const float* wc = w + (co * 16 + ci) * 27;
            #pragma unroll
            for (int kz = 0; kz < 3; kz++)
            #pragma unroll
            for (int ky = 0; ky < 3; ky++)
            #pragma unroll
            for (int kx = 0; kx < 3; kx++)
                acc += hc[kz * 25 + ky * 5 + kx] * wc[kz * 9 + ky * 3 + kx];
        }
        conv[t] = relu_bn(acc, g[co], b[co]);
    }
    __syncthreads();
    if (t < 8) {
        float m = -INFINITY;
        for (int dz = 0; dz < 2; dz++)
        for (int dy = 0; dy < 2; dy++)
        for (int dx = 0; dx < 2; dx++)
            m = fmaxf(m, conv[t * 27 + dz * 9 + dy * 3 + dx]);
        pooled[t] = m;
    }
    __syncthreads();
    if (t < 3) {
        float acc = blin[t];
        #pragma unroll
        for (int j = 0; j < 8; j++) acc += pooled[j] * wlin[t * 8 + j];
        pred_out[n * 3 + t] = acc;
    }
}

// ---------------- main path ----------------
// up[n,co,2i+k] += prev[n,ci,i] * w_up[co,ci,k]  (verified Round 4)
// Scatter-in-registers: thread owns full 26-deep z-column at (oy,ox);
// each loaded input feeds 4 kz taps -> 4 FMA per load, weights scalar.
__global__ void upsample_k(const float* __restrict__ prev, const float* __restrict__ wup,
                           float* __restrict__ U, int n0) {
    int blk = blockIdx.x;              // nl*32 + co
    int co = blk & 31;
    int nl = blk >> 5;
    int t = threadIdx.x;
    if (t >= 676) return;
    int oy = t / 26, ox = t % 26;
    int py = oy & 1, px = ox & 1;
    int iy0 = oy >> 1, ix0 = ox >> 1;
    float acc[26];
    #pragma unroll
    for (int i = 0; i < 26; i++) acc[i] = 0.f;
    const float* pb = prev + (size_t)(n0 + nl) * 32 * 1728;
    const float* wb = wup + (size_t)co * 2048;
    for (int ci = 0; ci < 32; ci++) {
        const float* wc = wb + ci * 64;
        const float* pc = pb + ci * 1728;
        #pragma unroll
        for (int dy = 0; dy < 2; dy++) {
            int iy = iy0 - dy;
            if (iy < 0 || iy >= 12) continue;
            int ky = py + 2 * dy;
            #pragma unroll
            for (int dx = 0; dx < 2; dx++) {
                int ix = ix0 - dx;
                if (ix < 0 || ix >= 12) continue;
                int kx = px + 2 * dx;
                float w0 = wc[0 * 16 + ky * 4 + kx];
                float w1 = wc[1 * 16 + ky * 4 + kx];
                float w2 = wc[2 * 16 + ky * 4 + kx];
                float w3 = wc[3 * 16 + ky * 4 + kx];
                const float* col = pc + iy * 12 + ix;
                #pragma unroll
                for (int iz = 0; iz < 12; iz++) {
                    float u = col[iz * 144];
                    acc[2 * iz + 0] += u * w0;
                    acc[2 * iz + 1] += u * w1;
                    acc[2 * iz + 2] += u * w2;
                    acc[2 * iz + 3] += u * w3;
                }
            }
        }
    }
    float* ub = U + ((size_t)nl * 32 + co) * 17576 + oy * 26 + ox;
    #pragma unroll
    for (int oz = 0; oz < 26; oz++) ub[oz * 676] = acc[oz];
}

// conv0: Cin=33 (ch 32 = tsdf), 26^3 -> 24^3. Thread: ZT=4 z x YT=3 y tile.
// block = ((nl*32+co)*6 + zg), 192 threads (ox = t%24, oy0 = (t/24)*3).
__global__ void conv0_k(const float* __restrict__ U, const float* __restrict__ tsdf,
                        const float* __restrict__ w, const float* __restrict__ g,
                        const float* __restrict__ b, float* __restrict__ X0, int n0) {
    int blk = blockIdx.x;
    int zg = blk % 6;
    int co = (blk / 6) & 31;
    int nl = blk / (6 * 32);
    int z0 = zg * 4;
    int t = threadIdx.x;
    int ox = t % 24, oy0 = (t / 24) * 3;
    float acc[3][4];
    #pragma unroll
    for (int a = 0; a < 3; a++)
    #pragma unroll
    for (int c = 0; c < 4; c++) acc[a][c] = 0.f;
    int zoff[6];
    #pragma unroll
    for (int j = 0; j < 6; j++) zoff[j] = (z0 + j) * 676;
    const float* ub = U + (size_t)nl * 32 * 17576;
    const float* wb = w + co * 891;
    for (int ci = 0; ci < 32; ci++) {
        float wr[27];
        #pragma unroll
        for (int j = 0; j < 27; j++) wr[j] = wb[ci * 27 + j];
        const float* uc = ub + ci * 17576;
        #pragma unroll
        for (int kx = 0; kx < 3; kx++) {
            #pragma unroll
            for (int yr = 0; yr < 5; yr++) {
                const float* col = uc + (oy0 + yr) * 26 + (ox + kx);
                float u0 = col[zoff[0]], u1 = col[zoff[1]], u2 = col[zoff[2]];
                float u3 = col[zoff[3]], u4 = col[zoff[4]], u5 = col[zoff[5]];
                #pragma unroll
                for (int ky = 0; ky < 3; ky++) {
                    int yo = yr - ky;
                    if (yo < 0 || yo >= 3) continue;       // compile-time
                    float s0 = wr[0 + ky * 3 + kx], s1 = wr[9 + ky * 3 + kx], s2 = wr[18 + ky * 3 + kx];
                    acc[yo][0] += u0 * s0 + u1 * s1 + u2 * s2;
                    acc[yo][1] += u1 * s0 + u2 * s1 + u3 * s2;
                    acc[yo][2] += u2 * s0 + u3 * s1 + u4 * s2;
                    acc[yo][3] += u3 * s0 + u4 * s1 + u5 * s2;
                }
            }
        }
    }
    {   // tsdf channel (ci = 32)
        int n = n0 + nl;
        int A = (n >> 4) * 16, B = ((n >> 2) & 3) * 16, C = (n & 3) * 16;
        float wr[27];
        #pragma unroll
        for (int j = 0; j < 27; j++) wr[j] = wb[864 + j];
        int tzoff[6];
        #pragma unroll
        for (int j = 0; j < 6; j++) tzoff[j] = (A + z0 + j) * 5476;
        #pragma unroll
        for (int kx = 0; kx < 3; kx++) {
            #pragma unroll
            for (int yr = 0; yr < 5; yr++) {
                const float* col = tsdf + (B + oy0 + yr) * 74 + (C + ox + kx);
                float u0 = col[tzoff[0]], u1 = col[tzoff[1]], u2 = col[tzoff[2]];
                float u3 = col[tzoff[3]], u4 = col[tzoff[4]], u5 = col[tzoff[5]];
                #pragma unroll
                for (int ky = 0; ky < 3; ky++) {
                    int yo = yr - ky;
                    if (yo < 0 || yo >= 3) continue;
                    float s0 = wr[0 + ky * 3 + kx], s1 = wr[9 + ky * 3 + kx], s2 = wr[18 + ky * 3 + kx];
                    acc[yo][0] += u0 * s0 + u1 * s1 + u2 * s2;
                    acc[yo][1] += u1 * s0 + u2 * s1 + u3 * s2;
                    acc[yo][2] += u2 * s0 + u3 * s1 + u4 * s2;
                    acc[yo][3] += u3 * s0 + u4 * s1 + u5 * s2;
                }
            }
        }
    }
    float gc = g[co], bc = b[co];
    #pragma unroll
    for (int yo = 0; yo < 3; yo++)
    #pragma unroll
    for (int zi = 0; zi < 4; zi++)
        X0[(((size_t)nl * 32 + co) * 24 + z0 + zi) * 576 + (oy0 + yo) * 24 + ox] =
            relu_bn(acc[yo][zi], gc, bc);
}

// conv1: 24^3 -> 22^3. ZT=4 (ragged last), YT=2. block ((nl*32+co)*6+zg), 256 thr (242).
__global__ void conv1_k(const float* __restrict__ X0, const float* __restrict__ w,
                        const float* __restrict__ g, const float* __restrict__ b,
                        float* __restrict__ X1) {
    int blk = blockIdx.x;
    int zg = blk % 6;
    int co = (blk / 6) & 31;
    int nl = blk / (6 * 32);
    int z0 = zg * 4;
    int t = threadIdx.x;
    if (t >= 242) return;
    int ox = t % 22, oy0 = (t / 22) * 2;
    float acc[2][4];
    #pragma unroll
    for (int a = 0; a < 2; a++)
    #pragma unroll
    for (int c = 0; c < 4; c++) acc[a][c] = 0.f;
    int zoff[6];
    #pragma unroll
    for (int j = 0; j < 6; j++) { int z = z0 + j; if (z > 23) z = 23; zoff[j] = z * 576; }
    const float* xb = X0 + (size_t)nl * 32 * 13824;
    const float* wb = w + co * 864;
    for (int ci = 0; ci < 32; ci++) {
        float wr[27];
        #pragma unroll
        for (int j = 0; j < 27; j++) wr[j] = wb[ci * 27 + j];
        const float* xc = xb + ci * 13824;
        #pragma unroll
        for (int kx = 0; kx < 3; kx++) {
            #pragma unroll
            for (int yr = 0; yr < 4; yr++) {
                const float* col = xc + (oy0 + yr) * 24 + (ox + kx);
                float u0 = col[zoff[0]], u1 = col[zoff[1]], u2 = col[zoff[2]];
                float u3 = col[zoff[3]], u4 = col[zoff[4]], u5 = col[zoff[5]];
                #pragma unroll
                for (int ky = 0; ky < 3; ky++) {
                    int yo = yr - ky;
                    if (yo < 0 || yo >= 2) continue;
                    float s0 = wr[0 + ky * 3 + kx], s1 = wr[9 + ky * 3 + kx], s2 = wr[18 + ky * 3 + kx];
                    acc[yo][0] += u0 * s0 + u1 * s1 + u2 * s2;
                    acc[yo][1] += u1 * s0 + u2 * s1 + u3 * s2;
                    acc[yo][2] += u2 * s0 + u3 * s1 + u4 * s2;
                    acc[yo][3] += u3 * s0 + u4 * s1 + u5 * s2;
                }
            }
        }
    }
    float gc = g[co], bc = b[co];
    #pragma unroll
    for (int yo = 0; yo < 2; yo++)
    #pragma unroll
    for (int zi = 0; zi < 4; zi++) {
        int oz = z0 + zi;
        if (oz < 22)
            X1[(((size_t)nl * 32 + co) * 22 + oz) * 484 + (oy0 + yo) * 22 + ox] =
                relu_bn(acc[yo][zi], gc, bc);
    }
}

// conv2: 22^3 -> 20^3, fused split_tree scatter. ZT=4 (clean), YT=2. 256 thr (200).
__global__ void conv2s_k(const float* __restrict__ X1, const float* __restrict__ w,
                         const float* __restrict__ g, const float* __restrict__ b,
                         float* __restrict__ out, int n0) {
    int blk = blockIdx.x;
    int zg = blk % 5;
    int co = (blk / 5) & 31;
    int nl = blk / (5 * 32);
    int z0 = zg * 4;
    int t = threadIdx.x;
    if (t >= 200) return;
    int ox = t % 20, oy0 = (t / 20) * 2;
    float acc[2][4];
    #pragma unroll
    for (int a = 0; a < 2; a++)
    #pragma unroll
    for (int c = 0; c < 4; c++) acc[a][c] = 0.f;
    int zoff[6];
    #pragma unroll
    for (int j = 0; j < 6; j++) zoff[j] = (z0 + j) * 484;
    const float* xb = X1 + (size_t)nl * 32 * 10648;
    const float* wb = w + co * 864;
    for (int ci = 0; ci < 32; ci++) {
        float wr[27];
        #pragma unroll
        for (int j = 0; j < 27; j++) wr[j] = wb[ci * 27 + j];
        const float* xc = xb + ci * 10648;
        #pragma unroll
        for (int kx = 0; kx < 3; kx++) {
            #pragma unroll
            for (int yr = 0; yr < 4; yr++) {
                const float* col = xc + (oy0 + yr) * 22 + (ox + kx);
                float u0 = col[zoff[0]], u1 = col[zoff[1]], u2 = col[zoff[2]];
                float u3 = col[zoff[3]], u4 = col[zoff[4]], u5 = col[zoff[5]];
                #pragma unroll
                for (int ky = 0; ky < 3; ky++) {
                    int yo = yr - ky;
                    if (yo < 0 || yo >= 2) continue;
                    float s0 = wr[0 + ky * 3 + kx], s1 = wr[9 + ky * 3 + kx], s2 = wr[18 + ky * 3 + kx];
                    acc[yo][0] += u0 * s0 + u1 * s1 + u2 * s2;
                    acc[yo][1] += u1 * s0 + u2 * s1 + u3 * s2;
                    acc[yo][2] += u2 * s0 + u3 * s1 + u4 * s2;
                    acc[yo][3] += u3 * s0 + u4 * s1 + u5 * s2;
                }
            }
        }
    }
    float gc = g[co], bc = b[co];
    int n = n0 + nl;
    #pragma unroll
    for (int yo = 0; yo < 2; yo++) {
        int oy = oy0 + yo;
        #pragma unroll
        for (int zi = 0; zi < 4; zi++) {
            int oz = z0 + zi;
            float v = relu_bn(acc[yo][zi], gc, bc);
            #pragma unroll
            for (int za = 0; za < 2; za++) {
                int z = oz - za * 8; if (z < 0 || z >= 12) continue;
                #pragma unroll
                for (int yb = 0; yb < 2; yb++) {
                    int y = oy - yb * 8; if (y < 0 || y >= 12) continue;
                    #pragma unroll
                    for (int xc2 = 0; xc2 < 2; xc2++) {
                        int x = ox - xc2 * 8; if (x < 0 || x >= 12) continue;
                        int s = za * 4 + yb * 2 + xc2;
                        out[((((size_t)n * 8 + s) * 32 + co) * 12 + z) * 144 + y * 12 + x] = v;
                    }
                }
            }
        }
    }
}

extern "C" void kernel_launch(void* const* d_in, const int* in_sizes, int n_in,
                              void* d_out, int out_size, void* d_ws, size_t ws_size,
                              hipStream_t stream) {
    const float* prev  = (const float*)d_in[0];
    const float* tsdf  = (const float*)d_in[1];
    const float* w_up  = (const float*)d_in[2];
    const float* w_c0  = (const float*)d_in[3];
    const float* g_c0  = (const float*)d_in[4];
    const float* b_c0  = (const float*)d_in[5];
    const float* w_c1  = (const float*)d_in[6];
    const float* g_c1  = (const float*)d_in[7];
    const float* b_c1  = (const float*)d_in[8];
    const float* w_c2  = (const float*)d_in[9];
    const float* g_c2  = (const float*)d_in[10];
    const float* b_c2  = (const float*)d_in[11];
    const float* w_p0  = (const float*)d_in[12];
    const float* g_p0  = (const float*)d_in[13];
    const float* b_p0  = (const float*)d_in[14];
    const float* w_p1  = (const float*)d_in[15];
    const float* g_p1  = (const float*)d_in[16];
    const float* b_p1  = (const float*)d_in[17];
    const float* w_lin = (const float*)d_in[18];
    const float* b_lin = (const float*)d_in[19];

    float* out = (float*)d_out;
    float* ws  = (float*)d_ws;

    // ---- prediction path ----
    float* h0 = ws;                       // 64*16*125 = 128000 floats
    pred_p0<<<64 * 16, 128, 0, stream>>>(prev, w_p0, g_p0, b_p0, h0);
    pred_p1<<<64, 256, 0, stream>>>(h0, w_p1, g_p1, b_p1, w_lin, b_lin,
                                    out + SUBTREE_FLOATS);

    // ---- main path, chunked; try 32 first, known-good fallback 16/8/... ----
    int chunk = 32;
    while (chunk > 1) {
        size_t need = (128000ull + (size_t)chunk * 32ull * (17576ull + 13824ull + 10648ull))
                      * sizeof(float);
        if (need <= ws_size) break;
        chunk >>= 1;
    }
    float* bufU  = ws + 128000;
    float* bufX0 = bufU  + (size_t)chunk * 32 * 17576;
    float* bufX1 = bufX0 + (size_t)chunk * 32 * 13824;

    for (int n0 = 0; n0 < NBLK; n0 += chunk) {
        upsample_k<<<chunk * 32,     704, 0, stream>>>(prev, w_up, bufU, n0);
        conv0_k  <<<chunk * 32 * 6,  192, 0, stream>>>(bufU, tsdf, w_c0, g_c0, b_c0, bufX0, n0);
        conv1_k  <<<chunk * 32 * 6,  256, 0, stream>>>(bufX0, w_c1, g_c1, b_c1, bufX1);
        conv2s_k <<<chunk * 32 * 5,  256, 0, stream>>>(bufX1, w_c2, g_c2, b_c2, out, n0);
    }
}

// Round 6
// 3285.633 us; speedup vs baseline: 3.4554x; 1.4709x over previous
//
#include <hip/hip_runtime.h>
#include <math.h>

// All f32. Math verified Round 4/5. This round: kill VGPR spills (launch_bounds),
// LDS-staged weights, 2x2x4 register tiles with float2 x-loads.
#define NBLK 64
#define SUBTREE_FLOATS (512ull*32ull*1728ull)   // 28,311,552

__device__ __forceinline__ float relu_bn(float acc, float g, float b) {
    float s = g * rsqrtf(1.0f + 1e-5f);
    float v = acc * s + b;
    return v > 0.f ? v : 0.f;
}

// ---------------- prediction path ----------------
__global__ __launch_bounds__(128, 2)
void pred_p0(const float* __restrict__ prev, const float* __restrict__ w,
             const float* __restrict__ g, const float* __restrict__ b,
             float* __restrict__ h0) {
    int blk = blockIdx.x;              // n*16 + co
    int n = blk >> 4, co = blk & 15;
    int t = threadIdx.x;
    __shared__ float wlds[864];
    for (int i = t; i < 864; i += 128) wlds[i] = w[co * 864 + i];
    __syncthreads();
    __shared__ float pz5[10 * 10 * 5];
    if (t < 100) {
        int oy = t / 10, ox = t % 10;
        float acc[10];
        #pragma unroll
        for (int i = 0; i < 10; i++) acc[i] = 0.f;
        const float* pb = prev + (size_t)n * 32 * 1728;
        for (int ci = 0; ci < 32; ci++) {
            float wr[27];
            #pragma unroll
            for (int j = 0; j < 27; j++) wr[j] = wlds[ci * 27 + j];
            const float* pc = pb + ci * 1728;
            #pragma unroll
            for (int ky = 0; ky < 3; ky++) {
                #pragma unroll
                for (int kx = 0; kx < 3; kx++) {
                    const float* col = pc + (oy + ky) * 12 + (ox + kx);
                    #pragma unroll
                    for (int j = 0; j < 12; j++) {
                        float u = col[j * 144];
                        #pragma unroll
                        for (int kz = 0; kz < 3; kz++) {
                            int zz = j - kz;
                            if (zz >= 0 && zz < 10)
                                acc[zz] += u * wr[kz * 9 + ky * 3 + kx];
                        }
                    }
                }
            }
        }
        float sc = g[co] * rsqrtf(1.0f + 1e-5f);
        float bi = b[co];
        #pragma unroll
        for (int p = 0; p < 5; p++) {
            float a0 = acc[2 * p]     * sc + bi; a0 = a0 > 0.f ? a0 : 0.f;
            float a1 = acc[2 * p + 1] * sc + bi; a1 = a1 > 0.f ? a1 : 0.f;
            pz5[(oy * 10 + ox) * 5 + p] = fmaxf(a0, a1);
        }
    }
    __syncthreads();
    if (t < 125) {
        int pz = t / 25, py = (t / 5) % 5, px = t % 5;
        float m = -INFINITY;
        #pragma unroll
        for (int dy = 0; dy < 2; dy++)
        #pragma unroll
        for (int dx = 0; dx < 2; dx++)
            m = fmaxf(m, pz5[((2 * py + dy) * 10 + 2 * px + dx) * 5 + pz]);
        h0[(n * 16 + co) * 125 + pz * 25 + py * 5 + px] = m;
    }
}

__global__ void pred_p1(const float* __restrict__ h0, const float* __restrict__ w,
                        const float* __restrict__ g, const float* __restrict__ b,
                        const float* __restrict__ wlin, const float* __restrict__ blin,
                        float* __restrict__ pred_out) {
    int n = blockIdx.x;
    __shared__ float conv[216];
    __shared__ float pooled[8];
    int t = threadIdx.x;
    if (t < 216) {
        int co = t / 27, r = t % 27;
        int oz = r / 9, oy = (r / 3) % 3, ox = r % 3;
        float acc = 0.f;
        for (int ci = 0; ci < 16; ci++) {
            const float* hc = h0 + (n * 16 + ci) * 125 + oz * 25 + oy * 5 + ox;
            const float* wc = w + (co * 16 + ci) * 27;
            #pragma unroll
            for (int kz = 0; kz < 3; kz++)
            #pragma unroll
            for (int ky = 0; ky < 3; ky++)
            #pragma unroll
            for (int kx = 0; kx < 3; kx++)
                acc += hc[kz * 25 + ky * 5 + kx] * wc[kz * 9 + ky * 3 + kx];
        }
        conv[t] = relu_bn(acc, g[co], b[co]);
    }
    __syncthreads();
    if (t < 8) {
        float m = -INFINITY;
        for (int dz = 0; dz < 2; dz++)
        for (int dy = 0; dy < 2; dy++)
        for (int dx = 0; dx < 2; dx++)
            m = fmaxf(m, conv[t * 27 + dz * 9 + dy * 3 + dx]);
        pooled[t] = m;
    }
    __syncthreads();
    if (t < 3) {
        float acc = blin[t];
        #pragma unroll
        for (int j = 0; j < 8; j++) acc += pooled[j] * wlin[t * 8 + j];
        pred_out[n * 3 + t] = acc;
    }
}

// ---------------- main path ----------------
// up[n,co,2i+k] += prev[n,ci,i] * w_up[co,ci,k]
__global__ __launch_bounds__(704, 1)
void upsample_k(const float* __restrict__ prev, const float* __restrict__ wup,
                float* __restrict__ U, int n0) {
    int blk = blockIdx.x;              // nl*32 + co
    int co = blk & 31;
    int nl = blk >> 5;
    int t = threadIdx.x;
    __shared__ float wlds[2048];
    for (int i = t; i < 2048; i += 704) wlds[i] = wup[(size_t)co * 2048 + i];
    __syncthreads();
    if (t >= 676) return;
    int oy = t / 26, ox = t % 26;
    int py = oy & 1, px = ox & 1;
    int iy0 = oy >> 1, ix0 = ox >> 1;
    float acc[26];
    #pragma unroll
    for (int i = 0; i < 26; i++) acc[i] = 0.f;
    const float* pb = prev + (size_t)(n0 + nl) * 32 * 1728;
    for (int ci = 0; ci < 32; ci++) {
        const float* wc = wlds + ci * 64;
        const float* pc = pb + ci * 1728;
        #pragma unroll
        for (int dy = 0; dy < 2; dy++) {
            int iy = iy0 - dy;
            if (iy < 0 || iy >= 12) continue;
            int ky = py + 2 * dy;
            #pragma unroll
            for (int dx = 0; dx < 2; dx++) {
                int ix = ix0 - dx;
                if (ix < 0 || ix >= 12) continue;
                int kx = px + 2 * dx;
                float w0 = wc[0 * 16 + ky * 4 + kx];
                float w1 = wc[1 * 16 + ky * 4 + kx];
                float w2 = wc[2 * 16 + ky * 4 + kx];
                float w3 = wc[3 * 16 + ky * 4 + kx];
                const float* col = pc + iy * 12 + ix;
                #pragma unroll
                for (int iz = 0; iz < 12; iz++) {
                    float u = col[iz * 144];
                    acc[2 * iz + 0] += u * w0;
                    acc[2 * iz + 1] += u * w1;
                    acc[2 * iz + 2] += u * w2;
                    acc[2 * iz + 3] += u * w3;
                }
            }
        }
    }
    float* ub = U + ((size_t)nl * 32 + co) * 17576 + oy * 26 + ox;
    #pragma unroll
    for (int oz = 0; oz < 26; oz++) ub[oz * 676] = acc[oz];
}

// conv0: Cin=33 (ch32 = tsdf), 26^3 -> 24^3. Tile 2y x 2x x 4z. 144 active / 192.
__global__ __launch_bounds__(192, 2)
void conv0_k(const float* __restrict__ U, const float* __restrict__ tsdf,
             const float* __restrict__ w, const float* __restrict__ g,
             const float* __restrict__ b, float* __restrict__ X0, int n0) {
    int blk = blockIdx.x;
    int zg = blk % 6;
    int co = (blk / 6) & 31;
    int nl = blk / (6 * 32);
    int z0 = zg * 4;
    int t = threadIdx.x;
    __shared__ float wlds[891];
    for (int i = t; i < 891; i += 192) wlds[i] = w[co * 891 + i];
    __syncthreads();
    if (t >= 144) return;
    int xt = t % 12, yt = t / 12;
    int x0 = xt * 2, y0 = yt * 2;
    float acc[2][2][4];
    #pragma unroll
    for (int a = 0; a < 2; a++)
    #pragma unroll
    for (int c = 0; c < 2; c++)
    #pragma unroll
    for (int d = 0; d < 4; d++) acc[a][c][d] = 0.f;
    const float* ub = U + (size_t)nl * 32 * 17576;
    for (int ci = 0; ci < 32; ci++) {
        float wr[27];
        #pragma unroll
        for (int j = 0; j < 27; j++) wr[j] = wlds[ci * 27 + j];
        const float* xc = ub + ci * 17576;
        #pragma unroll
        for (int yr = 0; yr < 4; yr++) {
            const float* row = xc + (y0 + yr) * 26 + x0;
            float u[6][4];
            #pragma unroll
            for (int j = 0; j < 6; j++) {
                float2 a2 = *(const float2*)(row + (z0 + j) * 676);
                float2 b2 = *(const float2*)(row + (z0 + j) * 676 + 2);
                u[j][0] = a2.x; u[j][1] = a2.y; u[j][2] = b2.x; u[j][3] = b2.y;
            }
            #pragma unroll
            for (int ky = 0; ky < 3; ky++) {
                int yo = yr - ky;
                if (yo < 0 || yo >= 2) continue;
                #pragma unroll
                for (int kz = 0; kz < 3; kz++)
                #pragma unroll
                for (int kx = 0; kx < 3; kx++) {
                    float wv = wr[kz * 9 + ky * 3 + kx];
                    #pragma unroll
                    for (int zi = 0; zi < 4; zi++)
                    #pragma unroll
                    for (int xo = 0; xo < 2; xo++)
                        acc[yo][xo][zi] += u[zi + kz][xo + kx] * wv;
                }
            }
        }
    }
    {   // tsdf channel (ci = 32)
        int n = n0 + nl;
        int A = (n >> 4) * 16, B = ((n >> 2) & 3) * 16, C = (n & 3) * 16;
        float wr[27];
        #pragma unroll
        for (int j = 0; j < 27; j++) wr[j] = wlds[864 + j];
        #pragma unroll
        for (int yr = 0; yr < 4; yr++) {
            const float* row = tsdf + (size_t)(B + y0 + yr) * 74 + C + x0;
            float u[6][4];
            #pragma unroll
            for (int j = 0; j < 6; j++) {
                float2 a2 = *(const float2*)(row + (size_t)(A + z0 + j) * 5476);
                float2 b2 = *(const float2*)(row + (size_t)(A + z0 + j) * 5476 + 2);
                u[j][0] = a2.x; u[j][1] = a2.y; u[j][2] = b2.x; u[j][3] = b2.y;
            }
            #pragma unroll
            for (int ky = 0; ky < 3; ky++) {
                int yo = yr - ky;
                if (yo < 0 || yo >= 2) continue;
                #pragma unroll
                for (int kz = 0; kz < 3; kz++)
                #pragma unroll
                for (int kx = 0; kx < 3; kx++) {
                    float wv = wr[kz * 9 + ky * 3 + kx];
                    #pragma unroll
                    for (int zi = 0; zi < 4; zi++)
                    #pragma unroll
                    for (int xo = 0; xo < 2; xo++)
                        acc[yo][xo][zi] += u[zi + kz][xo + kx] * wv;
                }
            }
        }
    }
    float gc = g[co], bc = b[co];
    #pragma unroll
    for (int yo = 0; yo < 2; yo++)
    #pragma unroll
    for (int xo = 0; xo < 2; xo++)
    #pragma unroll
    for (int zi = 0; zi < 4; zi++)
        X0[(((size_t)nl * 32 + co) * 24 + z0 + zi) * 576 + (y0 + yo) * 24 + (x0 + xo)] =
            relu_bn(acc[yo][xo][zi], gc, bc);
}

// conv1: 24^3 -> 22^3. Tile 2x2x4. 121 active / 128. zg=5 ragged (clamped loads).
__global__ __launch_bounds__(128, 2)
void conv1_k(const float* __restrict__ X0, const float* __restrict__ w,
             const float* __restrict__ g, const float* __restrict__ b,
             float* __restrict__ X1) {
    int blk = blockIdx.x;
    int zg = blk % 6;
    int co = (blk / 6) & 31;
    int nl = blk / (6 * 32);
    int z0 = zg * 4;
    int t = threadIdx.x;
    __shared__ float wlds[864];
    for (int i = t; i < 864; i += 128) wlds[i] = w[co * 864 + i];
    __syncthreads();
    if (t >= 121) return;
    int xt = t % 11, yt = t / 11;
    int x0 = xt * 2, y0 = yt * 2;
    float acc[2][2][4];
    #pragma unroll
    for (int a = 0; a < 2; a++)
    #pragma unroll
    for (int c = 0; c < 2; c++)
    #pragma unroll
    for (int d = 0; d < 4; d++) acc[a][c][d] = 0.f;
    int zoff[6];
    #pragma unroll
    for (int j = 0; j < 6; j++) { int z = z0 + j; if (z > 23) z = 23; zoff[j] = z * 576; }
    const float* xb = X0 + (size_t)nl * 32 * 13824;
    for (int ci = 0; ci < 32; ci++) {
        float wr[27];
        #pragma unroll
        for (int j = 0; j < 27; j++) wr[j] = wlds[ci * 27 + j];
        const float* xc = xb + ci * 13824;
        #pragma unroll
        for (int yr = 0; yr < 4; yr++) {
            const float* row = xc + (y0 + yr) * 24 + x0;
            float u[6][4];
            #pragma unroll
            for (int j = 0; j < 6; j++) {
                float2 a2 = *(const float2*)(row + zoff[j]);
                float2 b2 = *(const float2*)(row + zoff[j] + 2);
                u[j][0] = a2.x; u[j][1] = a2.y; u[j][2] = b2.x; u[j][3] = b2.y;
            }
            #pragma unroll
            for (int ky = 0; ky < 3; ky++) {
                int yo = yr - ky;
                if (yo < 0 || yo >= 2) continue;
                #pragma unroll
                for (int kz = 0; kz < 3; kz++)
                #pragma unroll
                for (int kx = 0; kx < 3; kx++) {
                    float wv = wr[kz * 9 + ky * 3 + kx];
                    #pragma unroll
                    for (int zi = 0; zi < 4; zi++)
                    #pragma unroll
                    for (int xo = 0; xo < 2; xo++)
                        acc[yo][xo][zi] += u[zi + kz][xo + kx] * wv;
                }
            }
        }
    }
    float gc = g[co], bc = b[co];
    #pragma unroll
    for (int yo = 0; yo < 2; yo++)
    #pragma unroll
    for (int xo = 0; xo < 2; xo++)
    #pragma unroll
    for (int zi = 0; zi < 4; zi++) {
        int oz = z0 + zi;
        if (oz < 22)
            X1[(((size_t)nl * 32 + co) * 22 + oz) * 484 + (y0 + yo) * 22 + (x0 + xo)] =
                relu_bn(acc[yo][xo][zi], gc, bc);
    }
}

// conv2: 22^3 -> 20^3, fused split_tree scatter. Tile 2x2x4. 100 active / 128.
__global__ __launch_bounds__(128, 2)
void conv2s_k(const float* __restrict__ X1, const float* __restrict__ w,
              const float* __restrict__ g, const float* __restrict__ b,
              float* __restrict__ out, int n0) {
    int blk = blockIdx.x;
    int zg = blk % 5;
    int co = (blk / 5) & 31;
    int nl = blk / (5 * 32);
    int z0 = zg * 4;
    int t = threadIdx.x;
    __shared__ float wlds[864];
    for (int i = t; i < 864; i += 128) wlds[i] = w[co * 864 + i];
    __syncthreads();
    if (t >= 100) return;
    int xt = t % 10, yt = t / 10;
    int x0 = xt * 2, y0 = yt * 2;
    float acc[2][2][4];
    #pragma unroll
    for (int a = 0; a < 2; a++)
    #pragma unroll
    for (int c = 0; c < 2; c++)
    #pragma unroll
    for (int d = 0; d < 4; d++) acc[a][c][d] = 0.f;
    const float* xb = X1 + (size_t)nl * 32 * 10648;
    for (int ci = 0; ci < 32; ci++) {
        float wr[27];
        #pragma unroll
        for (int j = 0; j < 27; j++) wr[j] = wlds[ci * 27 + j];
        const float* xc = xb + ci * 10648;
        #pragma unroll
        for (int yr = 0; yr < 4; yr++) {
            const float* row = xc + (y0 + yr) * 22 + x0;
            float u[6][4];
            #pragma unroll
            for (int j = 0; j < 6; j++) {
                float2 a2 = *(const float2*)(row + (z0 + j) * 484);
                float2 b2 = *(const float2*)(row + (z0 + j) * 484 + 2);
                u[j][0] = a2.x; u[j][1] = a2.y; u[j][2] = b2.x; u[j][3] = b2.y;
            }
            #pragma unroll
            for (int ky = 0; ky < 3; ky++) {
                int yo = yr - ky;
                if (yo < 0 || yo >= 2) continue;
                #pragma unroll
                for (int kz = 0; kz < 3; kz++)
                #pragma unroll
                for (int kx = 0; kx < 3; kx++) {
                    float wv = wr[kz * 9 + ky * 3 + kx];
                    #pragma unroll
                    for (int zi = 0; zi < 4; zi++)
                    #pragma unroll
                    for (int xo = 0; xo < 2; xo++)
                        acc[yo][xo][zi] += u[zi + kz][xo + kx] * wv;
                }
            }
        }
    }
    float gc = g[co], bc = b[co];
    int n = n0 + nl;
    #pragma unroll
    for (int yo = 0; yo < 2; yo++)
    #pragma unroll
    for (int xo = 0; xo < 2; xo++)
    #pragma unroll
    for (int zi = 0; zi < 4; zi++) {
        int oz = z0 + zi, oy = y0 + yo, ox = x0 + xo;
        float v = relu_bn(acc[yo][xo][zi], gc, bc);
        #pragma unroll
        for (int za = 0; za < 2; za++) {
            int z = oz - za * 8; if (z < 0 || z >= 12) continue;
            #pragma unroll
            for (int yb = 0; yb < 2; yb++) {
                int y = oy - yb * 8; if (y < 0 || y >= 12) continue;
                #pragma unroll
                for (int xc2 = 0; xc2 < 2; xc2++) {
                    int x = ox - xc2 * 8; if (x < 0 || x >= 12) continue;
                    int s = za * 4 + yb * 2 + xc2;
                    out[((((size_t)n * 8 + s) * 32 + co) * 12 + z) * 144 + y * 12 + x] = v;
                }
            }
        }
    }
}

extern "C" void kernel_launch(void* const* d_in, const int* in_sizes, int n_in,
                              void* d_out, int out_size, void* d_ws, size_t ws_size,
                              hipStream_t stream) {
    const float* prev  = (const float*)d_in[0];
    const float* tsdf  = (const float*)d_in[1];
    const float* w_up  = (const float*)d_in[2];
    const float* w_c0  = (const float*)d_in[3];
    const float* g_c0  = (const float*)d_in[4];
    const float* b_c0  = (const float*)d_in[5];
    const float* w_c1  = (const float*)d_in[6];
    const float* g_c1  = (const float*)d_in[7];
    const float* b_c1  = (const float*)d_in[8];
    const float* w_c2  = (const float*)d_in[9];
    const float* g_c2  = (const float*)d_in[10];
    const float* b_c2  = (const float*)d_in[11];
    const float* w_p0  = (const float*)d_in[12];
    const float* g_p0  = (const float*)d_in[13];
    const float* b_p0  = (const float*)d_in[14];
    const float* w_p1  = (const float*)d_in[15];
    const float* g_p1  = (const float*)d_in[16];
    const float* b_p1  = (const float*)d_in[17];
    const float* w_lin = (const float*)d_in[18];
    const float* b_lin = (const float*)d_in[19];

    float* out = (float*)d_out;
    float* ws  = (float*)d_ws;

    // ---- prediction path ----
    float* h0 = ws;                       // 64*16*125 = 128000 floats
    pred_p0<<<64 * 16, 128, 0, stream>>>(prev, w_p0, g_p0, b_p0, h0);
    pred_p1<<<64, 256, 0, stream>>>(h0, w_p1, g_p1, b_p1, w_lin, b_lin,
                                    out + SUBTREE_FLOATS);

    // ---- main path, chunked over coarse blocks ----
    int chunk = 32;
    while (chunk > 1) {
        size_t need = (128000ull + (size_t)chunk * 32ull * (17576ull + 13824ull + 10648ull))
                      * sizeof(float);
        if (need <= ws_size) break;
        chunk >>= 1;
    }
    float* bufU  = ws + 128000;
    float* bufX0 = bufU  + (size_t)chunk * 32 * 17576;
    float* bufX1 = bufX0 + (size_t)chunk * 32 * 13824;

    for (int n0 = 0; n0 < NBLK; n0 += chunk) {
        upsample_k<<<chunk * 32,     704, 0, stream>>>(prev, w_up, bufU, n0);
        conv0_k  <<<chunk * 32 * 6,  192, 0, stream>>>(bufU, tsdf, w_c0, g_c0, b_c0, bufX0, n0);
        conv1_k  <<<chunk * 32 * 6,  128, 0, stream>>>(bufX0, w_c1, g_c1, b_c1, bufX1);
        conv2s_k <<<chunk * 32 * 5,  128, 0, stream>>>(bufX1, w_c2, g_c2, b_c2, out, n0);
    }
}

// Round 7
// 969.786 us; speedup vs baseline: 11.7069x; 3.3880x over previous
//
#include <hip/hip_runtime.h>
#include <math.h>

// Pipeline: pred (f32, unchanged) | upsample (f32 vector, unchanged) -> tcvt ->
// MFMA tap-GEMM convs on channel-last bf16 (f32 accum), conv0 init from tsdf
// bias volume V, conv2 fused split-tree scatter (f32 out).
#define NBLK 64
#define SUBTREE_FLOATS (512ull*32ull*1728ull)   // 28,311,552

typedef __attribute__((ext_vector_type(8))) short bf16x8;   // 8 bf16 (4 VGPR)
typedef __attribute__((ext_vector_type(4))) float f32x4;    // MFMA acc

__device__ __forceinline__ unsigned short f2b(float f) {    // f32->bf16 RNE
    unsigned u = __float_as_uint(f);
    u = u + 0x7FFFu + ((u >> 16) & 1u);
    return (unsigned short)(u >> 16);
}
__device__ __forceinline__ float b2f(unsigned short h) {
    return __uint_as_float(((unsigned)h) << 16);
}
__device__ __forceinline__ float relu_bn(float acc, float g, float b) {
    float s = g * rsqrtf(1.0f + 1e-5f);
    float v = acc * s + b;
    return v > 0.f ? v : 0.f;
}

// ---------------- prediction path (f32, verified R4-R6) ----------------
__global__ __launch_bounds__(128, 2)
void pred_p0(const float* __restrict__ prev, const float* __restrict__ w,
             const float* __restrict__ g, const float* __restrict__ b,
             float* __restrict__ h0) {
    int blk = blockIdx.x;              // n*16 + co
    int n = blk >> 4, co = blk & 15;
    int t = threadIdx.x;
    __shared__ float wlds[864];
    for (int i = t; i < 864; i += 128) wlds[i] = w[co * 864 + i];
    __syncthreads();
    __shared__ float pz5[10 * 10 * 5];
    if (t < 100) {
        int oy = t / 10, ox = t % 10;
        float acc[10];
        #pragma unroll
        for (int i = 0; i < 10; i++) acc[i] = 0.f;
        const float* pb = prev + (size_t)n * 32 * 1728;
        for (int ci = 0; ci < 32; ci++) {
            float wr[27];
            #pragma unroll
            for (int j = 0; j < 27; j++) wr[j] = wlds[ci * 27 + j];
            const float* pc = pb + ci * 1728;
            #pragma unroll
            for (int ky = 0; ky < 3; ky++) {
                #pragma unroll
                for (int kx = 0; kx < 3; kx++) {
                    const float* col = pc + (oy + ky) * 12 + (ox + kx);
                    #pragma unroll
                    for (int j = 0; j < 12; j++) {
                        float u = col[j * 144];
                        #pragma unroll
                        for (int kz = 0; kz < 3; kz++) {
                            int zz = j - kz;
                            if (zz >= 0 && zz < 10)
                                acc[zz] += u * wr[kz * 9 + ky * 3 + kx];
                        }
                    }
                }
            }
        }
        float sc = g[co] * rsqrtf(1.0f + 1e-5f);
        float bi = b[co];
        #pragma unroll
        for (int p = 0; p < 5; p++) {
            float a0 = acc[2 * p]     * sc + bi; a0 = a0 > 0.f ? a0 : 0.f;
            float a1 = acc[2 * p + 1] * sc + bi; a1 = a1 > 0.f ? a1 : 0.f;
            pz5[(oy * 10 + ox) * 5 + p] = fmaxf(a0, a1);
        }
    }
    __syncthreads();
    if (t < 125) {
        int pz = t / 25, py = (t / 5) % 5, px = t % 5;
        float m = -INFINITY;
        #pragma unroll
        for (int dy = 0; dy < 2; dy++)
        #pragma unroll
        for (int dx = 0; dx < 2; dx++)
            m = fmaxf(m, pz5[((2 * py + dy) * 10 + 2 * px + dx) * 5 + pz]);
        h0[(n * 16 + co) * 125 + pz * 25 + py * 5 + px] = m;
    }
}

__global__ void pred_p1(const float* __restrict__ h0, const float* __restrict__ w,
                        const float* __restrict__ g, const float* __restrict__ b,
                        const float* __restrict__ wlin, const float* __restrict__ blin,
                        float* __restrict__ pred_out) {
    int n = blockIdx.x;
    __shared__ float conv[216];
    __shared__ float pooled[8];
    int t = threadIdx.x;
    if (t < 216) {
        int co = t / 27, r = t % 27;
        int oz = r / 9, oy = (r / 3) % 3, ox = r % 3;
        float acc = 0.f;
        for (int ci = 0; ci < 16; ci++) {
            const float* hc = h0 + (n * 16 + ci) * 125 + oz * 25 + oy * 5 + ox;
            const float* wc = w + (co * 16 + ci) * 27;
            #pragma unroll
            for (int kz = 0; kz < 3; kz++)
            #pragma unroll
            for (int ky = 0; ky < 3; ky++)
            #pragma unroll
            for (int kx = 0; kx < 3; kx++)
                acc += hc[kz * 25 + ky * 5 + kx] * wc[kz * 9 + ky * 3 + kx];
        }
        conv[t] = relu_bn(acc, g[co], b[co]);
    }
    __syncthreads();
    if (t < 8) {
        float m = -INFINITY;
        for (int dz = 0; dz < 2; dz++)
        for (int dy = 0; dy < 2; dy++)
        for (int dx = 0; dx < 2; dx++)
            m = fmaxf(m, conv[t * 27 + dz * 9 + dy * 3 + dx]);
        pooled[t] = m;
    }
    __syncthreads();
    if (t < 3) {
        float acc = blin[t];
        #pragma unroll
        for (int j = 0; j < 8; j++) acc += pooled[j] * wlin[t * 8 + j];
        pred_out[n * 3 + t] = acc;
    }
}

// ---------------- upsample (f32 vector, verified R6) ----------------
__global__ __launch_bounds__(704, 1)
void upsample_k(const float* __restrict__ prev, const float* __restrict__ wup,
                float* __restrict__ U, int n0) {
    int blk = blockIdx.x;              // nl*32 + co
    int co = blk & 31;
    int nl = blk >> 5;
    int t = threadIdx.x;
    __shared__ float wlds[2048];
    for (int i = t; i < 2048; i += 704) wlds[i] = wup[(size_t)co * 2048 + i];
    __syncthreads();
    if (t >= 676) return;
    int oy = t / 26, ox = t % 26;
    int py = oy & 1, px = ox & 1;
    int iy0 = oy >> 1, ix0 = ox >> 1;
    float acc[26];
    #pragma unroll
    for (int i = 0; i < 26; i++) acc[i] = 0.f;
    const float* pb = prev + (size_t)(n0 + nl) * 32 * 1728;
    for (int ci = 0; ci < 32; ci++) {
        const float* wc = wlds + ci * 64;
        const float* pc = pb + ci * 1728;
        #pragma unroll
        for (int dy = 0; dy < 2; dy++) {
            int iy = iy0 - dy;
            if (iy < 0 || iy >= 12) continue;
            int ky = py + 2 * dy;
            #pragma unroll
            for (int dx = 0; dx < 2; dx++) {
                int ix = ix0 - dx;
                if (ix < 0 || ix >= 12) continue;
                int kx = px + 2 * dx;
                float w0 = wc[0 * 16 + ky * 4 + kx];
                float w1 = wc[1 * 16 + ky * 4 + kx];
                float w2 = wc[2 * 16 + ky * 4 + kx];
                float w3 = wc[3 * 16 + ky * 4 + kx];
                const float* col = pc + iy * 12 + ix;
                #pragma unroll
                for (int iz = 0; iz < 12; iz++) {
                    float u = col[iz * 144];
                    acc[2 * iz + 0] += u * w0;
                    acc[2 * iz + 1] += u * w1;
                    acc[2 * iz + 2] += u * w2;
                    acc[2 * iz + 3] += u * w3;
                }
            }
        }
    }
    float* ub = U + ((size_t)nl * 32 + co) * 17576 + oy * 26 + ox;
    #pragma unroll
    for (int oz = 0; oz < 26; oz++) ub[oz * 676] = acc[oz];
}

// ---------------- transpose+cvt: U[nl][ci][26^3] f32 -> U_t[nl][26^3][32ci] bf16 ----
__global__ __launch_bounds__(256)
void tcvt(const float* __restrict__ U, unsigned short* __restrict__ Ut) {
    int z = blockIdx.x % 26;
    int nl = blockIdx.x / 26;
    const float* ub = U + (size_t)nl * 32 * 17576 + z * 676;
    unsigned short* ob = Ut + ((size_t)nl * 17576 + (size_t)z * 676) * 32;
    for (int pos = threadIdx.x; pos < 676; pos += 256) {
        unsigned short v[32];
        #pragma unroll
        for (int ci = 0; ci < 32; ci++) v[ci] = f2b(ub[(size_t)ci * 17576 + pos]);
        ushort4* o = (ushort4*)(ob + (size_t)pos * 32);
        #pragma unroll
        for (int j = 0; j < 8; j++)
            o[j] = make_ushort4(v[4 * j], v[4 * j + 1], v[4 * j + 2], v[4 * j + 3]);
    }
}

// ---------------- weight prep: w[co][ci][27] f32 -> Wt[tap][co][ci] bf16 ----------
__global__ void wprep(const float* __restrict__ w, unsigned short* __restrict__ Wt,
                      int wstride) {
    int i = blockIdx.x * 256 + threadIdx.x;
    if (i >= 27648) return;
    int tap = i >> 10, rem = i & 1023, co = rem >> 5, ci = rem & 31;
    Wt[i] = f2b(w[co * wstride + ci * 27 + tap]);
}

// ---------------- tsdf bias volume: V[zz][yy][xx][co] bf16 (72^3) ----------------
__global__ __launch_bounds__(128)
void vkern(const float* __restrict__ tsdf, const float* __restrict__ w_c0,
           unsigned short* __restrict__ V) {
    int yy = blockIdx.x % 72, zz = blockIdx.x / 72;
    int xx = threadIdx.x;
    if (xx >= 72) return;
    float tv[27];
    #pragma unroll
    for (int kz = 0; kz < 3; kz++)
    #pragma unroll
    for (int ky = 0; ky < 3; ky++)
    #pragma unroll
    for (int kx = 0; kx < 3; kx++)
        tv[kz * 9 + ky * 3 + kx] = tsdf[(size_t)(zz + kz) * 5476 + (yy + ky) * 74 + (xx + kx)];
    unsigned short* o = V + (((size_t)zz * 72 + yy) * 72 + xx) * 32;
    for (int co = 0; co < 32; co++) {
        float a = 0.f;
        const float* wc = w_c0 + co * 891 + 864;   // tsdf channel (ci=32) taps
        #pragma unroll
        for (int j = 0; j < 27; j++) a += tv[j] * wc[j];
        o[co] = f2b(a);
    }
}

// ---------------- MFMA tap-GEMM conv ----------------
// out[co][z][y][x] = sum_{tap,ci} Wt[tap][co][ci] * in_t[z+kz][y+ky][x+kx][ci]
// MFMA 16x16x32 bf16: A[m=lane&15][k=quad*8+j], B[n=lane&15][k=quad*8+j],
// D[row=quad*4+reg][col=lane&15]  (m=co-in-tile, n=spatial, k=ci).
// MODE 0: bf16 ch-last out | 1: + acc init from V | 2: f32 split-tree scatter out
template<int SIN, int SOUT, int MODE, int TPW>
__global__ __launch_bounds__(256, 2)
void conv_mfma(const unsigned short* __restrict__ in_t,
               const unsigned short* __restrict__ Wt,
               const float* __restrict__ gg, const float* __restrict__ bb,
               unsigned short* __restrict__ out_t, float* __restrict__ out_f,
               const unsigned short* __restrict__ V, int n0)
{
    constexpr int NPOS = SOUT * SOUT;
    constexpr int NT = (NPOS + 15) / 16;
    int z  = blockIdx.x % SOUT;
    int nl = blockIdx.x / SOUT;
    int lane = threadIdx.x & 63, wave = threadIdx.x >> 6;
    int ln = lane & 15, quad = lane >> 4;

    int nidx[TPW], py[TPW], px[TPW];
    const unsigned short* bptr[TPW];
    const unsigned short* inb =
        in_t + (size_t)nl * SIN * SIN * SIN * 32 + (size_t)z * SIN * SIN * 32;
    #pragma unroll
    for (int t = 0; t < TPW; t++) {
        int ti = wave + 4 * t;
        int n = ti * 16 + ln;
        nidx[t] = (ti < NT && n < NPOS) ? n : NPOS;     // NPOS => inactive lane-tile
        int nc = (nidx[t] < NPOS) ? nidx[t] : (NPOS - 1);
        py[t] = nc / SOUT; px[t] = nc % SOUT;
        bptr[t] = inb + ((size_t)py[t] * SIN + px[t]) * 32 + quad * 8;
    }
    f32x4 acc[TPW][2];
    if constexpr (MODE == 1) {
        int n = n0 + nl;
        int A = (n >> 4) * 16, B = ((n >> 2) & 3) * 16, C = (n & 3) * 16;
        #pragma unroll
        for (int t = 0; t < TPW; t++) {
            const unsigned short* vp =
                V + (((size_t)(A + z) * 72 + (B + py[t])) * 72 + (C + px[t])) * 32 + quad * 4;
            ushort4 v0 = *(const ushort4*)vp;
            ushort4 v1 = *(const ushort4*)(vp + 16);
            acc[t][0][0] = b2f(v0.x); acc[t][0][1] = b2f(v0.y);
            acc[t][0][2] = b2f(v0.z); acc[t][0][3] = b2f(v0.w);
            acc[t][1][0] = b2f(v1.x); acc[t][1][1] = b2f(v1.y);
            acc[t][1][2] = b2f(v1.z); acc[t][1][3] = b2f(v1.w);
        }
    } else {
        #pragma unroll
        for (int t = 0; t < TPW; t++) {
            #pragma unroll
            for (int c = 0; c < 2; c++)
                acc[t][c] = (f32x4){0.f, 0.f, 0.f, 0.f};
        }
    }

    #pragma unroll 1
    for (int tap = 0; tap < 27; tap++) {
        int kz = tap / 9, ky = (tap % 9) / 3, kx = tap % 3;
        const unsigned short* wp = Wt + tap * 1024 + ln * 32 + quad * 8;
        bf16x8 Af0 = *(const bf16x8*)wp;            // co tile 0
        bf16x8 Af1 = *(const bf16x8*)(wp + 512);    // co tile 1 (+16co*32ci)
        size_t off = ((size_t)kz * SIN * SIN + (size_t)ky * SIN + kx) * 32;
        #pragma unroll
        for (int t = 0; t < TPW; t++) {
            bf16x8 Bf = *(const bf16x8*)(bptr[t] + off);
            acc[t][0] = __builtin_amdgcn_mfma_f32_16x16x32_bf16(Af0, Bf, acc[t][0], 0, 0, 0);
            acc[t][1] = __builtin_amdgcn_mfma_f32_16x16x32_bf16(Af1, Bf, acc[t][1], 0, 0, 0);
        }
    }

    int cobase = quad * 4;
    f32x4 g0 = *(const f32x4*)(gg + cobase);
    f32x4 g1 = *(const f32x4*)(gg + 16 + cobase);
    f32x4 b0 = *(const f32x4*)(bb + cobase);
    f32x4 b1 = *(const f32x4*)(bb + 16 + cobase);

    #pragma unroll
    for (int t = 0; t < TPW; t++) {
        if (nidx[t] >= NPOS) continue;
        float v0[4], v1[4];
        #pragma unroll
        for (int r = 0; r < 4; r++) {
            v0[r] = relu_bn(acc[t][0][r], g0[r], b0[r]);
            v1[r] = relu_bn(acc[t][1][r], g1[r], b1[r]);
        }
        if constexpr (MODE != 2) {
            unsigned short* o = out_t +
                ((size_t)nl * SOUT * SOUT * SOUT + (size_t)z * NPOS + nidx[t]) * 32 + cobase;
            *(ushort4*)o        = make_ushort4(f2b(v0[0]), f2b(v0[1]), f2b(v0[2]), f2b(v0[3]));
            *(ushort4*)(o + 16) = make_ushort4(f2b(v1[0]), f2b(v1[1]), f2b(v1[2]), f2b(v1[3]));
        } else {
            int n = n0 + nl;
            int oy = py[t], ox = px[t];
            #pragma unroll
            for (int za = 0; za < 2; za++) {
                int zz = z - za * 8; if (zz < 0 || zz >= 12) continue;
                #pragma unroll
                for (int yb = 0; yb < 2; yb++) {
                    int yy = oy - yb * 8; if (yy < 0 || yy >= 12) continue;
                    #pragma unroll
                    for (int xc = 0; xc < 2; xc++) {
                        int xx = ox - xc * 8; if (xx < 0 || xx >= 12) continue;
                        int s = za * 4 + yb * 2 + xc;
                        float* ob = out_f + ((size_t)n * 8 + s) * 32 * 1728
                                    + zz * 144 + yy * 12 + xx;
                        #pragma unroll
                        for (int r = 0; r < 4; r++) {
                            ob[(size_t)(cobase + r) * 1728]      = v0[r];
                            ob[(size_t)(16 + cobase + r) * 1728] = v1[r];
                        }
                    }
                }
            }
        }
    }
}

extern "C" void kernel_launch(void* const* d_in, const int* in_sizes, int n_in,
                              void* d_out, int out_size, void* d_ws, size_t ws_size,
                              hipStream_t stream) {
    const float* prev  = (const float*)d_in[0];
    const float* tsdf  = (const float*)d_in[1];
    const float* w_up  = (const float*)d_in[2];
    const float* w_c0  = (const float*)d_in[3];
    const float* g_c0  = (const float*)d_in[4];
    const float* b_c0  = (const float*)d_in[5];
    const float* w_c1  = (const float*)d_in[6];
    const float* g_c1  = (const float*)d_in[7];
    const float* b_c1  = (const float*)d_in[8];
    const float* w_c2  = (const float*)d_in[9];
    const float* g_c2  = (const float*)d_in[10];
    const float* b_c2  = (const float*)d_in[11];
    const float* w_p0  = (const float*)d_in[12];
    const float* g_p0  = (const float*)d_in[13];
    const float* b_p0  = (const float*)d_in[14];
    const float* w_p1  = (const float*)d_in[15];
    const float* g_p1  = (const float*)d_in[16];
    const float* b_p1  = (const float*)d_in[17];
    const float* w_lin = (const float*)d_in[18];
    const float* b_lin = (const float*)d_in[19];

    float* out = (float*)d_out;
    char* wsb  = (char*)d_ws;

    size_t off = 0;
    float* h0 = (float*)(wsb + off);            off += 512000;      // 64*16*125 f32
    unsigned short* Wt0 = (unsigned short*)(wsb + off); off += 55296;
    unsigned short* Wt1 = (unsigned short*)(wsb + off); off += 55296;
    unsigned short* Wt2 = (unsigned short*)(wsb + off); off += 55296;
    unsigned short* V   = (unsigned short*)(wsb + off); off += 23887872; // 72^3*32 bf16
    size_t fixed = off;

    int chunk = 32;
    while (chunk > 1) {
        size_t need = fixed + (size_t)chunk *
            (2249728ull /*U f32*/ + 1124864ull /*U_t*/ + 884736ull /*X0_t*/ + 681472ull /*X1_t*/);
        if (need <= ws_size) break;
        chunk >>= 1;
    }
    float* U            = (float*)(wsb + off);          off += (size_t)chunk * 2249728;
    unsigned short* U_t = (unsigned short*)(wsb + off); off += (size_t)chunk * 1124864;
    unsigned short* X0t = (unsigned short*)(wsb + off); off += (size_t)chunk * 884736;
    unsigned short* X1t = (unsigned short*)(wsb + off);

    // prediction path + preps
    pred_p0<<<64 * 16, 128, 0, stream>>>(prev, w_p0, g_p0, b_p0, h0);
    pred_p1<<<64, 256, 0, stream>>>(h0, w_p1, g_p1, b_p1, w_lin, b_lin,
                                    out + SUBTREE_FLOATS);
    wprep<<<108, 256, 0, stream>>>(w_c0, Wt0, 891);
    wprep<<<108, 256, 0, stream>>>(w_c1, Wt1, 864);
    wprep<<<108, 256, 0, stream>>>(w_c2, Wt2, 864);
    vkern<<<72 * 72, 128, 0, stream>>>(tsdf, w_c0, V);

    for (int n0 = 0; n0 < NBLK; n0 += chunk) {
        upsample_k<<<chunk * 32, 704, 0, stream>>>(prev, w_up, U, n0);
        tcvt<<<chunk * 26, 256, 0, stream>>>(U, U_t);
        conv_mfma<26, 24, 1, 9><<<chunk * 24, 256, 0, stream>>>(
            U_t, Wt0, g_c0, b_c0, X0t, nullptr, V, n0);
        conv_mfma<24, 22, 0, 8><<<chunk * 22, 256, 0, stream>>>(
            X0t, Wt1, g_c1, b_c1, X1t, nullptr, nullptr, n0);
        conv_mfma<22, 20, 2, 7><<<chunk * 20, 256, 0, stream>>>(
            X1t, Wt2, g_c2, b_c2, nullptr, out, nullptr, n0);
    }
}